// Round 1
// baseline (3652.895 us; speedup 1.0000x reference)
//
#include <hip/hip_runtime.h>
#include <math.h>

#define BN 64
#define KIN 1024
#define DOUT 512
#define NN 2048
#define TBLK 128
#define NBLK 16

__device__ __forceinline__ float softplus_f(float x) {
  return x > 0.f ? x + log1pf(expf(-x)) : log1pf(expf(x));
}
__device__ __forceinline__ float apply_nl(int id, float v) {
  switch (id) {
    case 0: return fmaxf(v, 0.f);
    case 1: return tanhf(v);
    case 2: return v >= 0.f ? v : 0.01f * v;
    case 3: return v;
    case 4: return sinf(v);
    case 5: return softplus_f(v);
    default: return -softplus_f(-v);  // 6: softminus
  }
}

// ---------------- adj dtype detection & normalization ----------------
// byte-mode: random 0/1 bytes -> some nonzero byte at i%4!=0, all bytes in {0,1}
// int32-mode: bytes at i%4!=0 all zero, bytes at i%4==0 in {0,1}
// f32-mode:  bytes outside {0,1} (0x3F/0x80) appear
__global__ void detect_adj(const unsigned char* __restrict__ a, int* __restrict__ flag) {
  __shared__ int s01, soff;
  if (threadIdx.x == 0) { s01 = 1; soff = 0; }
  __syncthreads();
  int l01 = 1, loff = 0;
  for (int i = threadIdx.x; i < 65536; i += blockDim.x) {
    unsigned char v = a[i];
    if (v > 1) l01 = 0;
    if ((i & 3) && v) loff = 1;
  }
  if (!l01) atomicAnd(&s01, 0);
  if (loff) atomicOr(&soff, 1);
  __syncthreads();
  if (threadIdx.x == 0) {
    int mode;
    if (s01) mode = soff ? 1 : 0;  // 1=byte, 0=int32
    else mode = 2;                 // float32
    *flag = mode;
  }
}

__global__ void normalize_adj(const unsigned char* __restrict__ a,
                              const int* __restrict__ flag,
                              unsigned char* __restrict__ out) {
  size_t i = (size_t)blockIdx.x * blockDim.x + threadIdx.x;
  int mode = flag[0];
  unsigned char r;
  if (mode == 1)      r = (a[i] != 0);
  else if (mode == 0) r = (((const int*)a)[i] != 0);
  else                r = (((const float*)a)[i] != 0.f);
  out[i] = r;
}

// ---------------- X transpose: X[64][1024] -> XT[1024][64] ----------------
__global__ void transpose_x(const float* __restrict__ X, float* __restrict__ XT) {
  int g = blockIdx.x * blockDim.x + threadIdx.x;  // 65536
  int k = g >> 6, b = g & 63;
  XT[g] = X[(size_t)b * KIN + k];
}

// ---------------- unified partial GEMM (K-split, atomic accumulate) ----------------
// accT[col][64] += sum over k-chunk of AT[k][b] * W[k][col] * mask
// MODE 0: no mask; MODE 1: element mask adj[k][col]; MODE 2: row mask adj[k][NN-1]
template <int MODE>
__global__ __launch_bounds__(256) void gemm_partial(
    const float* __restrict__ AT,          // [Ktot][64]
    const float* __restrict__ W,           // [Ktot][ldw]
    const unsigned char* __restrict__ adj, // normalized [NN][NN]
    float* __restrict__ accT,              // [colsTot][64], pre-zeroed
    int ldw, int col0, int ncols, int kPerChunk, int nColTiles)
{
  const int ct = blockIdx.x % nColTiles;
  const int kc = blockIdx.x / nColTiles;
  const int c0 = ct * 64;              // local col-tile base
  const int k0 = kc * kPerChunk;
  const int t = threadIdx.x;
  const int tb = t >> 4;               // 0..15 : b-quad
  const int tc = t & 15;               // 0..15 : c-quad

  __shared__ __align__(16) float At[16][64];
  __shared__ __align__(16) float Wt[16][64];

  float acc[4][4] = {};

  const int sk = t >> 4;   // staging k-row 0..15
  const int sq = t & 15;   // staging quad 0..15

  for (int ks = k0; ks < k0 + kPerChunk; ks += 16) {
    // stage A tile (coalesced float4)
    const float4 av = *(const float4*)(AT + (size_t)(ks + sk) * 64 + sq * 4);
    *(float4*)(&At[sk][sq * 4]) = av;
    // stage W tile with mask + col guard
    {
      const float* wrow = W + (size_t)(ks + sk) * ldw + col0;
      float w[4];
      float rowmask = 1.f;
      if (MODE == 2) rowmask = (float)adj[(size_t)(ks + sk) * NN + (NN - 1)];
#pragma unroll
      for (int e = 0; e < 4; ++e) {
        int cl = c0 + sq * 4 + e;
        float wv = 0.f;
        if (cl < ncols) {
          wv = wrow[cl];
          if (MODE == 1) wv *= (float)adj[(size_t)(ks + sk) * NN + col0 + cl];
          if (MODE == 2) wv *= rowmask;
        }
        w[e] = wv;
      }
      *(float4*)(&Wt[sk][sq * 4]) = make_float4(w[0], w[1], w[2], w[3]);
    }
    __syncthreads();
#pragma unroll
    for (int kk = 0; kk < 16; ++kk) {
      float a4[4], w4[4];
#pragma unroll
      for (int e = 0; e < 4; ++e) a4[e] = At[kk][tb * 4 + e];
#pragma unroll
      for (int e = 0; e < 4; ++e) w4[e] = Wt[kk][tc * 4 + e];
#pragma unroll
      for (int i = 0; i < 4; ++i)
#pragma unroll
        for (int j = 0; j < 4; ++j) acc[i][j] = fmaf(a4[i], w4[j], acc[i][j]);
    }
    __syncthreads();
  }

#pragma unroll
  for (int j = 0; j < 4; ++j) {
    int cl = c0 + tc * 4 + j;
    if (cl < ncols) {
      float* dst = accT + (size_t)(col0 + cl) * 64 + tb * 4;
#pragma unroll
      for (int i = 0; i < 4; ++i) atomicAdd(dst + i, acc[i][j]);
    }
  }
}

// ---------------- init finish: nl + mask -> curT ----------------
__global__ void init_finish(const float* __restrict__ out0accT, const float* __restrict__ b0,
                            const unsigned char* __restrict__ adjN, const int* __restrict__ nl_idx,
                            float* __restrict__ curT) {
  int g = blockIdx.x * blockDim.x + threadIdx.x;  // 2048*64
  int n = g >> 6;
  float v = out0accT[g] + b0[n];
  v = apply_nl(nl_idx[0], v);
  curT[g] = adjN[n] ? v : 0.f;  // adj row 0
}

// ---------------- sequential in-block solver (1 wave, shift-register) ----------------
__global__ __launch_bounds__(64, 1) void seq_block(
    const float* __restrict__ Wmid, const unsigned char* __restrict__ adjN,
    const int* __restrict__ nlidx, const float* __restrict__ bmid,
    const float* __restrict__ CfullT, float* __restrict__ curT,
    int n0, int size)
{
  __shared__ __align__(16) float wmS[TBLK][TBLK];  // left-packed upper triangle, 64 KiB
  const int b = threadIdx.x;

  // stage wmS: row j, slot q holds masked W_mid[n0+j][n0+j+1+q] (0 beyond triangle)
  for (int j = 0; j < TBLK; ++j) {
    const int rem = size - 1 - j;
#pragma unroll
    for (int h = 0; h < 2; ++h) {
      int q = h * 64 + b;
      float w = 0.f;
      if (q < rem) {
        size_t idx = (size_t)(n0 + j) * NN + (size_t)(n0 + j + 1 + q);
        w = Wmid[idx] * (float)adjN[idx];
      }
      wmS[j][q] = w;
    }
  }
  __syncthreads();

  float val[TBLK + 1];
  val[TBLK] = 0.f;
#pragma unroll
  for (int q = 0; q < TBLK; ++q) {
    int n = n0 + q;
    val[q] = (q < size) ? (CfullT[(size_t)n * 64 + b] + bmid[n]) : 0.f;
  }

  float nextInit = curT[(size_t)n0 * 64 + b];
  int nextId = nlidx[n0];

#define DO_QUARTER(Q)                                                    \
  {                                                                      \
    _Pragma("unroll") for (int q8 = 0; q8 < 8; ++q8) {                   \
      const int qq = (Q)*8 + q8;                                         \
      float4 w4 = wr[qq];                                                \
      val[4 * qq + 0] = fmaf(delta, w4.x, val[4 * qq + 1]);              \
      val[4 * qq + 1] = fmaf(delta, w4.y, val[4 * qq + 2]);              \
      val[4 * qq + 2] = fmaf(delta, w4.z, val[4 * qq + 3]);              \
      val[4 * qq + 3] = fmaf(delta, w4.w, val[4 * qq + 4]);              \
    }                                                                    \
  }

  for (int j = 0; j < size; ++j) {
    const float iv = nextInit;
    const int id = __builtin_amdgcn_readfirstlane(nextId);
    if (j + 1 < size) {  // software prefetch of next step's init value / nl id
      nextInit = curT[(size_t)(n0 + j + 1) * 64 + b];
      nextId = nlidx[n0 + j + 1];
    }
    const float nv = apply_nl(id, val[0]);
    const float delta = nv - iv;
    curT[(size_t)(n0 + j) * 64 + b] = nv;  // fire-and-forget

    const int rem = size - 1 - j;
    const float4* wr = (const float4*)(&wmS[j][0]);
    if (rem > 0) DO_QUARTER(0);
    if (rem > 32) DO_QUARTER(1);
    if (rem > 64) DO_QUARTER(2);
    if (rem > 96) DO_QUARTER(3);
  }
#undef DO_QUARTER
}

// ---------------- final finish: out = nl(outaccT + b_out) ----------------
__global__ void final_finish(const float* __restrict__ outaccT, const float* __restrict__ bout,
                             const int* __restrict__ nlidx, float* __restrict__ out) {
  int g = blockIdx.x * blockDim.x + threadIdx.x;  // 512*64
  int c = g >> 6, b = g & 63;
  float v = outaccT[g] + bout[c];
  v = apply_nl(nlidx[NN - 1], v);
  out[(size_t)b * DOUT + c] = v;
}

// ---------------- state transpose: curT[n][b] -> state[b][n] ----------------
__global__ __launch_bounds__(256) void transpose_state(const float* __restrict__ curT,
                                                       float* __restrict__ stateOut) {
  __shared__ float tile[64][65];
  int n0 = blockIdx.x * 64;
  for (int r = 0; r < 16; ++r) {
    int e = r * 256 + threadIdx.x;
    tile[e >> 6][e & 63] = curT[(size_t)(n0 + (e >> 6)) * 64 + (e & 63)];
  }
  __syncthreads();
  for (int r = 0; r < 16; ++r) {
    int e = r * 256 + threadIdx.x;
    int bb = e >> 6, nn2 = e & 63;
    stateOut[(size_t)bb * NN + n0 + nn2] = tile[nn2][bb];
  }
}

extern "C" void kernel_launch(void* const* d_in, const int* in_sizes, int n_in,
                              void* d_out, int out_size, void* d_ws, size_t ws_size,
                              hipStream_t stream) {
  const float* X = (const float*)d_in[0];
  const unsigned char* adj = (const unsigned char*)d_in[1];
  const int* nl_idx = (const int*)d_in[2];
  const float* W0 = (const float*)d_in[3];
  const float* b0 = (const float*)d_in[4];
  const float* W_mid = (const float*)d_in[5];
  const float* b_mid = (const float*)d_in[6];
  const float* W_out = (const float*)d_in[7];
  const float* b_out = (const float*)d_in[8];
  float* out = (float*)d_out;              // [64][512]
  float* stateOut = out + BN * DOUT;       // [64][2048]

  char* ws = (char*)d_ws;
  unsigned char* adjN = (unsigned char*)(ws + 0);       // 4 MiB
  int* flag = (int*)(ws + 4194304);                     // 4 B (pad to 256)
  float* XT = (float*)(ws + 4194560);                   // 256 KiB
  float* curT = (float*)(ws + 4456704);                 // 512 KiB
  float* out0accT = (float*)(ws + 4980992);             // 512 KiB
  float* CfullT = (float*)(ws + 5505280);               // 512 KiB
  float* outaccT = (float*)(ws + 6029568);              // 128 KiB -> end 6160640

  // zero all atomic-accumulate regions (contiguous)
  hipMemsetAsync(out0accT, 0, 524288 + 524288 + 131072, stream);

  detect_adj<<<1, 256, 0, stream>>>(adj, flag);
  normalize_adj<<<16384, 256, 0, stream>>>(adj, flag, adjN);
  transpose_x<<<256, 256, 0, stream>>>(X, XT);

  // node 0: out0accT = X @ W0   (K=1024: 32 col-tiles x 8 k-chunks)
  gemm_partial<0><<<256, 256, 0, stream>>>(XT, W0, adjN, out0accT, NN, 0, NN, 128, 32);
  init_finish<<<512, 256, 0, stream>>>(out0accT, b0, adjN, nl_idx, curT);

  // middle nodes 1..2046 in blocks of 128
  for (int i = 0; i < NBLK; ++i) {
    int n0 = 1 + i * TBLK;
    int size = NN - 1 - n0;
    if (size > TBLK) size = TBLK;
    // CfullT[n] = curT-snapshot @ (W_mid[:,n]*adj[:,n])  (K=2048: 2 col-tiles x 32 k-chunks)
    gemm_partial<1><<<64, 256, 0, stream>>>(curT, W_mid, adjN, CfullT, NN, n0, size, 64, 2);
    seq_block<<<1, 64, 0, stream>>>(W_mid, adjN, nl_idx, b_mid, CfullT, curT, n0, size);
  }

  // final node (K=2048: 8 col-tiles x 16 k-chunks)
  gemm_partial<2><<<128, 256, 0, stream>>>(curT, W_out, adjN, outaccT, DOUT, 0, DOUT, 128, 8);
  final_finish<<<128, 256, 0, stream>>>(outaccT, b_out, nl_idx, out);
  transpose_state<<<32, 256, 0, stream>>>(curT, stateOut);
}

// Round 2
// 1964.081 us; speedup vs baseline: 1.8598x; 1.8598x over previous
//
#include <hip/hip_runtime.h>
#include <math.h>

#define BN 64
#define KIN 1024
#define DOUT 512
#define NN 2048
#define TBLK 128
#define NBLK 16

__device__ __forceinline__ float softplus_f(float x) {
  return x > 0.f ? x + log1pf(expf(-x)) : log1pf(expf(x));
}
__device__ __forceinline__ float apply_nl(int id, float v) {
  switch (id) {
    case 0: return fmaxf(v, 0.f);
    case 1: return tanhf(v);
    case 2: return v >= 0.f ? v : 0.01f * v;
    case 3: return v;
    case 4: return sinf(v);
    case 5: return softplus_f(v);
    default: return -softplus_f(-v);  // 6: softminus
  }
}

// ---------------- adj dtype detection & normalization ----------------
__global__ void detect_adj(const unsigned char* __restrict__ a, int* __restrict__ flag) {
  __shared__ int s01, soff;
  if (threadIdx.x == 0) { s01 = 1; soff = 0; }
  __syncthreads();
  int l01 = 1, loff = 0;
  for (int i = threadIdx.x; i < 65536; i += blockDim.x) {
    unsigned char v = a[i];
    if (v > 1) l01 = 0;
    if ((i & 3) && v) loff = 1;
  }
  if (!l01) atomicAnd(&s01, 0);
  if (loff) atomicOr(&soff, 1);
  __syncthreads();
  if (threadIdx.x == 0) {
    int mode;
    if (s01) mode = soff ? 1 : 0;  // 1=byte, 0=int32
    else mode = 2;                 // float32
    *flag = mode;
  }
}

__global__ void normalize_adj(const unsigned char* __restrict__ a,
                              const int* __restrict__ flag,
                              unsigned char* __restrict__ out) {
  size_t i = (size_t)blockIdx.x * blockDim.x + threadIdx.x;
  int mode = flag[0];
  unsigned char r;
  if (mode == 1)      r = (a[i] != 0);
  else if (mode == 0) r = (((const int*)a)[i] != 0);
  else                r = (((const float*)a)[i] != 0.f);
  out[i] = r;
}

// ---------------- X transpose: X[64][1024] -> XT[1024][64] ----------------
__global__ void transpose_x(const float* __restrict__ X, float* __restrict__ XT) {
  int g = blockIdx.x * blockDim.x + threadIdx.x;  // 65536
  int k = g >> 6, b = g & 63;
  XT[g] = X[(size_t)b * KIN + k];
}

// ---------------- unified partial GEMM (K-split, atomic accumulate) ----------------
template <int MODE>
__global__ __launch_bounds__(256) void gemm_partial(
    const float* __restrict__ AT,          // [Ktot][64]
    const float* __restrict__ W,           // [Ktot][ldw]
    const unsigned char* __restrict__ adj, // normalized [NN][NN]
    float* __restrict__ accT,              // [colsTot][64], pre-zeroed
    int ldw, int col0, int ncols, int kPerChunk, int nColTiles)
{
  const int ct = blockIdx.x % nColTiles;
  const int kc = blockIdx.x / nColTiles;
  const int c0 = ct * 64;
  const int k0 = kc * kPerChunk;
  const int t = threadIdx.x;
  const int tb = t >> 4;
  const int tc = t & 15;

  __shared__ __align__(16) float At[16][64];
  __shared__ __align__(16) float Wt[16][64];

  float acc[4][4] = {};

  const int sk = t >> 4;
  const int sq = t & 15;

  for (int ks = k0; ks < k0 + kPerChunk; ks += 16) {
    const float4 av = *(const float4*)(AT + (size_t)(ks + sk) * 64 + sq * 4);
    *(float4*)(&At[sk][sq * 4]) = av;
    {
      const float* wrow = W + (size_t)(ks + sk) * ldw + col0;
      float w[4];
      float rowmask = 1.f;
      if (MODE == 2) rowmask = (float)adj[(size_t)(ks + sk) * NN + (NN - 1)];
#pragma unroll
      for (int e = 0; e < 4; ++e) {
        int cl = c0 + sq * 4 + e;
        float wv = 0.f;
        if (cl < ncols) {
          wv = wrow[cl];
          if (MODE == 1) wv *= (float)adj[(size_t)(ks + sk) * NN + col0 + cl];
          if (MODE == 2) wv *= rowmask;
        }
        w[e] = wv;
      }
      *(float4*)(&Wt[sk][sq * 4]) = make_float4(w[0], w[1], w[2], w[3]);
    }
    __syncthreads();
#pragma unroll
    for (int kk = 0; kk < 16; ++kk) {
      float a4[4], w4[4];
#pragma unroll
      for (int e = 0; e < 4; ++e) a4[e] = At[kk][tb * 4 + e];
#pragma unroll
      for (int e = 0; e < 4; ++e) w4[e] = Wt[kk][tc * 4 + e];
#pragma unroll
      for (int i = 0; i < 4; ++i)
#pragma unroll
        for (int j = 0; j < 4; ++j) acc[i][j] = fmaf(a4[i], w4[j], acc[i][j]);
    }
    __syncthreads();
  }

#pragma unroll
  for (int j = 0; j < 4; ++j) {
    int cl = c0 + tc * 4 + j;
    if (cl < ncols) {
      float* dst = accT + (size_t)(col0 + cl) * 64 + tb * 4;
#pragma unroll
      for (int i = 0; i < 4; ++i) atomicAdd(dst + i, acc[i][j]);
    }
  }
}

// ---------------- init finish: nl + mask -> curT ----------------
__global__ void init_finish(const float* __restrict__ out0accT, const float* __restrict__ b0,
                            const unsigned char* __restrict__ adjN, const int* __restrict__ nl_idx,
                            float* __restrict__ curT) {
  int g = blockIdx.x * blockDim.x + threadIdx.x;
  int n = g >> 6;
  float v = out0accT[g] + b0[n];
  v = apply_nl(nl_idx[0], v);
  curT[g] = adjN[n] ? v : 0.f;
}

// ---------------- sequential in-block solver: 4 waves, chunked triangular ----------------
// Wave w owns slots [w*32, w*32+32). Chunk c == wave c's slot range.
// Phase A (owner): 32 serial steps fully in registers, broadcasting deltas via LDS.
// Phase B (waves > c): rank-32 update of their slots.
__global__ __launch_bounds__(256, 1) void seq_block(
    const float* __restrict__ Wmid, const unsigned char* __restrict__ adjN,
    const int* __restrict__ nlidx, const float* __restrict__ bmid,
    const float* __restrict__ CfullT, float* __restrict__ curT,
    int n0, int size)
{
  __shared__ __align__(16) float wmS[TBLK][TBLK];   // 64 KiB: wmS[j][q] masked, 0 outside triangle
  __shared__ __align__(16) float deltaS[32][64];    // 8 KiB broadcast buffer
  const int tid = threadIdx.x;
  const int wv = tid >> 6;
  const int b = tid & 63;
  const int qbase = wv * 32;

  // stage weights: wmS[j][q] = (q>j && j<size && q<size) ? Wmid[n0+j][n0+q]*adj : 0
  for (int it = tid; it < TBLK * (TBLK / 4); it += 256) {
    int j = it >> 5;
    int q4 = (it & 31) * 4;
    float w[4];
#pragma unroll
    for (int e = 0; e < 4; ++e) {
      int q = q4 + e;
      float v = 0.f;
      if (q > j && j < size && q < size) {
        size_t idx = (size_t)(n0 + j) * NN + (size_t)(n0 + q);
        v = Wmid[idx] * (float)adjN[idx];
      }
      w[e] = v;
    }
    *(float4*)(&wmS[j][q4]) = make_float4(w[0], w[1], w[2], w[3]);
  }

  // preload this wave's slot state (all static register indices)
  float val[32], iv[32];
  int id[32];
#pragma unroll
  for (int l = 0; l < 32; ++l) {
    int q = qbase + l;
    int n = n0 + q;
    bool ok = q < size;
    val[l] = ok ? (CfullT[(size_t)n * 64 + b] + bmid[n]) : 0.f;
    iv[l] = ok ? curT[(size_t)n * 64 + b] : 0.f;
    id[l] = ok ? nlidx[n] : 3;
  }
  __syncthreads();

  for (int c = 0; c < 4; ++c) {
    if (wv == c) {
      // -------- Phase A: serial over own 32 slots --------
#pragma unroll
      for (int jj = 0; jj < 32; ++jj) {
        const int j = c * 32 + jj;
        float delta = 0.f;
        if (j < size) {  // wave-uniform
          float nv = apply_nl(__builtin_amdgcn_readfirstlane(id[jj]), val[jj]);
          delta = nv - iv[jj];
          curT[(size_t)(n0 + j) * 64 + b] = nv;  // fire-and-forget
        }
        deltaS[jj][b] = delta;
        if (jj < 31) {
          const float4* wr = (const float4*)(&wmS[j][qbase]);
#pragma unroll
          for (int g = (jj + 1) / 4; g < 8; ++g) {
            float4 w4 = wr[g];
            float wt[4] = {w4.x, w4.y, w4.z, w4.w};
#pragma unroll
            for (int e = 0; e < 4; ++e) {
              const int l = g * 4 + e;
              if (l > jj) val[l] = fmaf(delta, wt[e], val[l]);
            }
          }
        }
      }
    }
    __syncthreads();  // deltas visible
    if (wv > c) {
      // -------- Phase B: rank-32 update of own slots --------
#pragma unroll
      for (int jj = 0; jj < 32; ++jj) {
        const int j = c * 32 + jj;
        const float delta = deltaS[jj][b];
        const float4* wr = (const float4*)(&wmS[j][qbase]);
#pragma unroll
        for (int l8 = 0; l8 < 8; ++l8) {
          float4 w4 = wr[l8];
          val[l8 * 4 + 0] = fmaf(delta, w4.x, val[l8 * 4 + 0]);
          val[l8 * 4 + 1] = fmaf(delta, w4.y, val[l8 * 4 + 1]);
          val[l8 * 4 + 2] = fmaf(delta, w4.z, val[l8 * 4 + 2]);
          val[l8 * 4 + 3] = fmaf(delta, w4.w, val[l8 * 4 + 3]);
        }
      }
    }
    __syncthreads();  // deltaS reusable
  }
}

// ---------------- final finish ----------------
__global__ void final_finish(const float* __restrict__ outaccT, const float* __restrict__ bout,
                             const int* __restrict__ nlidx, float* __restrict__ out) {
  int g = blockIdx.x * blockDim.x + threadIdx.x;
  int c = g >> 6, b = g & 63;
  float v = outaccT[g] + bout[c];
  v = apply_nl(nlidx[NN - 1], v);
  out[(size_t)b * DOUT + c] = v;
}

// ---------------- state transpose ----------------
__global__ __launch_bounds__(256) void transpose_state(const float* __restrict__ curT,
                                                       float* __restrict__ stateOut) {
  __shared__ float tile[64][65];
  int n0 = blockIdx.x * 64;
  for (int r = 0; r < 16; ++r) {
    int e = r * 256 + threadIdx.x;
    tile[e >> 6][e & 63] = curT[(size_t)(n0 + (e >> 6)) * 64 + (e & 63)];
  }
  __syncthreads();
  for (int r = 0; r < 16; ++r) {
    int e = r * 256 + threadIdx.x;
    int bb = e >> 6, nn2 = e & 63;
    stateOut[(size_t)bb * NN + n0 + nn2] = tile[nn2][bb];
  }
}

extern "C" void kernel_launch(void* const* d_in, const int* in_sizes, int n_in,
                              void* d_out, int out_size, void* d_ws, size_t ws_size,
                              hipStream_t stream) {
  const float* X = (const float*)d_in[0];
  const unsigned char* adj = (const unsigned char*)d_in[1];
  const int* nl_idx = (const int*)d_in[2];
  const float* W0 = (const float*)d_in[3];
  const float* b0 = (const float*)d_in[4];
  const float* W_mid = (const float*)d_in[5];
  const float* b_mid = (const float*)d_in[6];
  const float* W_out = (const float*)d_in[7];
  const float* b_out = (const float*)d_in[8];
  float* out = (float*)d_out;
  float* stateOut = out + BN * DOUT;

  char* ws = (char*)d_ws;
  unsigned char* adjN = (unsigned char*)(ws + 0);       // 4 MiB
  int* flag = (int*)(ws + 4194304);
  float* XT = (float*)(ws + 4194560);                   // 256 KiB
  float* curT = (float*)(ws + 4456704);                 // 512 KiB
  float* out0accT = (float*)(ws + 4980992);             // 512 KiB
  float* CfullT = (float*)(ws + 5505280);               // 512 KiB
  float* outaccT = (float*)(ws + 6029568);              // 128 KiB

  hipMemsetAsync(out0accT, 0, 524288 + 524288 + 131072, stream);

  detect_adj<<<1, 256, 0, stream>>>(adj, flag);
  normalize_adj<<<16384, 256, 0, stream>>>(adj, flag, adjN);
  transpose_x<<<256, 256, 0, stream>>>(X, XT);

  gemm_partial<0><<<256, 256, 0, stream>>>(XT, W0, adjN, out0accT, NN, 0, NN, 128, 32);
  init_finish<<<512, 256, 0, stream>>>(out0accT, b0, adjN, nl_idx, curT);

  for (int i = 0; i < NBLK; ++i) {
    int n0 = 1 + i * TBLK;
    int size = NN - 1 - n0;
    if (size > TBLK) size = TBLK;
    gemm_partial<1><<<64, 256, 0, stream>>>(curT, W_mid, adjN, CfullT, NN, n0, size, 64, 2);
    seq_block<<<1, 256, 0, stream>>>(W_mid, adjN, nl_idx, b_mid, CfullT, curT, n0, size);
  }

  gemm_partial<2><<<128, 256, 0, stream>>>(curT, W_out, adjN, outaccT, DOUT, 0, DOUT, 128, 8);
  final_finish<<<128, 256, 0, stream>>>(outaccT, b_out, nl_idx, out);
  transpose_state<<<32, 256, 0, stream>>>(curT, stateOut);
}

// Round 3
// 1128.308 us; speedup vs baseline: 3.2375x; 1.7407x over previous
//
#include <hip/hip_runtime.h>
#include <math.h>

#define BN 64
#define KIN 1024
#define DOUT 512
#define NN 2048
#define TBLK 128
#define NBLK 16

__device__ __forceinline__ float softplus_f(float x) {
  float e = __expf(-fabsf(x));
  return fmaxf(x, 0.f) + __logf(1.f + e);
}
__device__ __forceinline__ float apply_nl(int id, float v) {
  switch (id) {
    case 0: return fmaxf(v, 0.f);
    case 1: { float e = __expf(2.f * v); return fmaf(-2.f, __builtin_amdgcn_rcpf(e + 1.f), 1.f); }
    case 2: return v >= 0.f ? v : 0.01f * v;
    case 3: return v;
    case 4: return __sinf(v);
    case 5: return softplus_f(v);
    default: return v - softplus_f(v);  // -softplus(-v)
  }
}

// ---------------- adj dtype detection & normalization ----------------
__global__ void detect_adj(const unsigned char* __restrict__ a, int* __restrict__ flag) {
  __shared__ int s01, soff;
  if (threadIdx.x == 0) { s01 = 1; soff = 0; }
  __syncthreads();
  int l01 = 1, loff = 0;
  for (int i = threadIdx.x; i < 65536; i += blockDim.x) {
    unsigned char v = a[i];
    if (v > 1) l01 = 0;
    if ((i & 3) && v) loff = 1;
  }
  if (!l01) atomicAnd(&s01, 0);
  if (loff) atomicOr(&soff, 1);
  __syncthreads();
  if (threadIdx.x == 0) {
    int mode;
    if (s01) mode = soff ? 1 : 0;  // 1=byte, 0=int32
    else mode = 2;                 // float32
    *flag = mode;
  }
}

__global__ void normalize_adj(const unsigned char* __restrict__ a,
                              const int* __restrict__ flag,
                              unsigned char* __restrict__ out) {
  size_t i = (size_t)blockIdx.x * blockDim.x + threadIdx.x;
  int mode = flag[0];
  unsigned char r;
  if (mode == 1)      r = (a[i] != 0);
  else if (mode == 0) r = (((const int*)a)[i] != 0);
  else                r = (((const float*)a)[i] != 0.f);
  out[i] = r;
}

// ---------------- X transpose ----------------
__global__ void transpose_x(const float* __restrict__ X, float* __restrict__ XT) {
  int g = blockIdx.x * blockDim.x + threadIdx.x;
  int k = g >> 6, b = g & 63;
  XT[g] = X[(size_t)b * KIN + k];
}

// ---------------- pack in-block triangles: wpack[i][j][q] ----------------
// wpack[i][j][q] = (q>j && j<size_i && q<size_i) ? Wmid[n0+j][n0+q]*adj : 0
__global__ __launch_bounds__(256) void pack_wmid(const float* __restrict__ Wmid,
                                                 const unsigned char* __restrict__ adjN,
                                                 float* __restrict__ wpack) {
  int g = blockIdx.x * 256 + threadIdx.x;  // 65536 float4s
  int i = g >> 12;
  int rem = g & 4095;
  int j = rem >> 5;
  int q4 = (rem & 31) * 4;
  int n0 = 1 + i * TBLK;
  int size = NN - 1 - n0;
  if (size > TBLK) size = TBLK;
  float w[4];
#pragma unroll
  for (int e = 0; e < 4; ++e) {
    int q = q4 + e;
    float v = 0.f;
    if (q > j && j < size && q < size) {
      size_t idx = (size_t)(n0 + j) * NN + (size_t)(n0 + q);
      v = Wmid[idx] * (float)adjN[idx];
    }
    w[e] = v;
  }
  *(float4*)(wpack + (size_t)g * 4) = make_float4(w[0], w[1], w[2], w[3]);
}

// ---------------- unified partial GEMM (K-split, atomic accumulate) ----------------
template <int MODE>
__global__ __launch_bounds__(256) void gemm_partial(
    const float* __restrict__ AT, const float* __restrict__ W,
    const unsigned char* __restrict__ adj, float* __restrict__ accT,
    int ldw, int col0, int ncols, int kPerChunk, int nColTiles)
{
  const int ct = blockIdx.x % nColTiles;
  const int kc = blockIdx.x / nColTiles;
  const int c0 = ct * 64;
  const int k0 = kc * kPerChunk;
  const int t = threadIdx.x;
  const int tb = t >> 4;
  const int tc = t & 15;

  __shared__ __align__(16) float At[16][64];
  __shared__ __align__(16) float Wt[16][64];

  float acc[4][4] = {};
  const int sk = t >> 4;
  const int sq = t & 15;

  for (int ks = k0; ks < k0 + kPerChunk; ks += 16) {
    const float4 av = *(const float4*)(AT + (size_t)(ks + sk) * 64 + sq * 4);
    *(float4*)(&At[sk][sq * 4]) = av;
    {
      const float* wrow = W + (size_t)(ks + sk) * ldw + col0;
      float w[4];
      float rowmask = 1.f;
      if (MODE == 2) rowmask = (float)adj[(size_t)(ks + sk) * NN + (NN - 1)];
#pragma unroll
      for (int e = 0; e < 4; ++e) {
        int cl = c0 + sq * 4 + e;
        float wv = 0.f;
        if (cl < ncols) {
          wv = wrow[cl];
          if (MODE == 1) wv *= (float)adj[(size_t)(ks + sk) * NN + col0 + cl];
          if (MODE == 2) wv *= rowmask;
        }
        w[e] = wv;
      }
      *(float4*)(&Wt[sk][sq * 4]) = make_float4(w[0], w[1], w[2], w[3]);
    }
    __syncthreads();
#pragma unroll
    for (int kk = 0; kk < 16; ++kk) {
      float a4[4], w4[4];
#pragma unroll
      for (int e = 0; e < 4; ++e) a4[e] = At[kk][tb * 4 + e];
#pragma unroll
      for (int e = 0; e < 4; ++e) w4[e] = Wt[kk][tc * 4 + e];
#pragma unroll
      for (int i = 0; i < 4; ++i)
#pragma unroll
        for (int j = 0; j < 4; ++j) acc[i][j] = fmaf(a4[i], w4[j], acc[i][j]);
    }
    __syncthreads();
  }

#pragma unroll
  for (int j = 0; j < 4; ++j) {
    int cl = c0 + tc * 4 + j;
    if (cl < ncols) {
      float* dst = accT + (size_t)(col0 + cl) * 64 + tb * 4;
#pragma unroll
      for (int i = 0; i < 4; ++i) atomicAdd(dst + i, acc[i][j]);
    }
  }
}

// ---------------- init finish ----------------
__global__ void init_finish(const float* __restrict__ out0accT, const float* __restrict__ b0,
                            const unsigned char* __restrict__ adjN, const int* __restrict__ nl_idx,
                            float* __restrict__ curT) {
  int g = blockIdx.x * blockDim.x + threadIdx.x;
  int n = g >> 6;
  float v = out0accT[g] + b0[n];
  v = apply_nl(nl_idx[0], v);
  curT[g] = adjN[n] ? v : 0.f;
}

// ---------------- sequential in-block solver: 4 waves, chunked triangular ----------------
__global__ __launch_bounds__(256, 1) void seq_block(
    const float* __restrict__ wpack, const int* __restrict__ nlidx,
    const float* __restrict__ bmid, const float* __restrict__ CfullT,
    float* __restrict__ curT, int blk, int n0, int size)
{
  __shared__ __align__(16) float wmS[TBLK][TBLK];   // 64 KiB packed triangle (zeros below diag)
  __shared__ __align__(16) float deltaS[32][64];    // 8 KiB broadcast
  const int tid = threadIdx.x;
  const int wv = tid >> 6;
  const int b = tid & 63;
  const int qbase = wv * 32;

  // ---- stage weights: clean float4 copy of pre-packed triangle (reg-staged) ----
  const float4* src = (const float4*)(wpack + (size_t)blk * TBLK * TBLK);
  float4 stg[16];
#pragma unroll
  for (int it = 0; it < 16; ++it) stg[it] = src[it * 256 + tid];

  // ---- preload this wave's slot state (independent, overlaps staging latency) ----
  float val[32], iv[32];
  int id[32];
#pragma unroll
  for (int l = 0; l < 32; ++l) {
    int q = qbase + l;
    int n = n0 + q;
    bool ok = q < size;
    val[l] = ok ? (CfullT[(size_t)n * 64 + b] + bmid[n]) : 0.f;
    iv[l] = ok ? curT[(size_t)n * 64 + b] : 0.f;
    id[l] = ok ? nlidx[n] : 3;
  }

#pragma unroll
  for (int it = 0; it < 16; ++it)
    *(float4*)(&((float*)wmS)[(size_t)(it * 256 + tid) * 4]) = stg[it];
  __syncthreads();

#pragma unroll 1
  for (int c = 0; c < 4; ++c) {
    if (wv == c) {
      // -------- Phase A: serial over own 32 slots, row prefetched --------
      const int jbase = c * 32;
      float4 wrow[8];
      {
        const float4* wr = (const float4*)(&wmS[jbase][qbase]);
#pragma unroll
        for (int g2 = 0; g2 < 8; ++g2) wrow[g2] = wr[g2];
      }
#pragma unroll
      for (int jj = 0; jj < 32; ++jj) {
        const int j = jbase + jj;
        float delta = 0.f;
        if (j < size) {  // wave-uniform
          float nv = apply_nl(__builtin_amdgcn_readfirstlane(id[jj]), val[jj]);
          delta = nv - iv[jj];
          curT[(size_t)(n0 + j) * 64 + b] = nv;  // fire-and-forget
        }
        deltaS[jj][b] = delta;
        float4 wnext[8];
        if (jj < 31) {
          const float4* wr2 = (const float4*)(&wmS[j + 1][qbase]);
#pragma unroll
          for (int g2 = 0; g2 < 8; ++g2) wnext[g2] = wr2[g2];
        }
        // packed zeros on/below diagonal make guards unnecessary; start at first live group
#pragma unroll
        for (int g2 = (jj + 1) >> 2; g2 < 8; ++g2) {
          val[g2 * 4 + 0] = fmaf(delta, wrow[g2].x, val[g2 * 4 + 0]);
          val[g2 * 4 + 1] = fmaf(delta, wrow[g2].y, val[g2 * 4 + 1]);
          val[g2 * 4 + 2] = fmaf(delta, wrow[g2].z, val[g2 * 4 + 2]);
          val[g2 * 4 + 3] = fmaf(delta, wrow[g2].w, val[g2 * 4 + 3]);
        }
        if (jj < 31) {
#pragma unroll
          for (int g2 = 0; g2 < 8; ++g2) wrow[g2] = wnext[g2];
        }
      }
    }
    __syncthreads();  // deltas visible
    if (wv > c) {
      // -------- Phase B: rank-32 update of own slots --------
#pragma unroll
      for (int jj = 0; jj < 32; ++jj) {
        const int j = c * 32 + jj;
        const float delta = deltaS[jj][b];
        const float4* wr = (const float4*)(&wmS[j][qbase]);
#pragma unroll
        for (int l8 = 0; l8 < 8; ++l8) {
          float4 w4 = wr[l8];
          val[l8 * 4 + 0] = fmaf(delta, w4.x, val[l8 * 4 + 0]);
          val[l8 * 4 + 1] = fmaf(delta, w4.y, val[l8 * 4 + 1]);
          val[l8 * 4 + 2] = fmaf(delta, w4.z, val[l8 * 4 + 2]);
          val[l8 * 4 + 3] = fmaf(delta, w4.w, val[l8 * 4 + 3]);
        }
      }
    }
    __syncthreads();  // deltaS reusable
  }
}

// ---------------- final finish ----------------
__global__ void final_finish(const float* __restrict__ outaccT, const float* __restrict__ bout,
                             const int* __restrict__ nlidx, float* __restrict__ out) {
  int g = blockIdx.x * blockDim.x + threadIdx.x;
  int c = g >> 6, b = g & 63;
  float v = outaccT[g] + bout[c];
  v = apply_nl(nlidx[NN - 1], v);
  out[(size_t)b * DOUT + c] = v;
}

// ---------------- state transpose ----------------
__global__ __launch_bounds__(256) void transpose_state(const float* __restrict__ curT,
                                                       float* __restrict__ stateOut) {
  __shared__ float tile[64][65];
  int n0 = blockIdx.x * 64;
  for (int r = 0; r < 16; ++r) {
    int e = r * 256 + threadIdx.x;
    tile[e >> 6][e & 63] = curT[(size_t)(n0 + (e >> 6)) * 64 + (e & 63)];
  }
  __syncthreads();
  for (int r = 0; r < 16; ++r) {
    int e = r * 256 + threadIdx.x;
    int bb = e >> 6, nn2 = e & 63;
    stateOut[(size_t)bb * NN + n0 + nn2] = tile[nn2][bb];
  }
}

extern "C" void kernel_launch(void* const* d_in, const int* in_sizes, int n_in,
                              void* d_out, int out_size, void* d_ws, size_t ws_size,
                              hipStream_t stream) {
  const float* X = (const float*)d_in[0];
  const unsigned char* adj = (const unsigned char*)d_in[1];
  const int* nl_idx = (const int*)d_in[2];
  const float* W0 = (const float*)d_in[3];
  const float* b0 = (const float*)d_in[4];
  const float* W_mid = (const float*)d_in[5];
  const float* b_mid = (const float*)d_in[6];
  const float* W_out = (const float*)d_in[7];
  const float* b_out = (const float*)d_in[8];
  float* out = (float*)d_out;
  float* stateOut = out + BN * DOUT;

  char* ws = (char*)d_ws;
  unsigned char* adjN = (unsigned char*)(ws + 0);       // 4 MiB
  int* flag = (int*)(ws + 4194304);
  float* XT = (float*)(ws + 4194560);                   // 256 KiB
  float* curT = (float*)(ws + 4456704);                 // 512 KiB
  float* out0accT = (float*)(ws + 4980992);             // 512 KiB
  float* CfullT = (float*)(ws + 5505280);               // 512 KiB
  float* outaccT = (float*)(ws + 6029568);              // 128 KiB
  float* wpack = (float*)(ws + 6160640);                // 1 MiB -> end 7209216

  hipMemsetAsync(out0accT, 0, 524288 + 524288 + 131072, stream);

  detect_adj<<<1, 256, 0, stream>>>(adj, flag);
  normalize_adj<<<16384, 256, 0, stream>>>(adj, flag, adjN);
  transpose_x<<<256, 256, 0, stream>>>(X, XT);
  pack_wmid<<<256, 256, 0, stream>>>(W_mid, adjN, wpack);

  gemm_partial<0><<<256, 256, 0, stream>>>(XT, W0, adjN, out0accT, NN, 0, NN, 128, 32);
  init_finish<<<512, 256, 0, stream>>>(out0accT, b0, adjN, nl_idx, curT);

  for (int i = 0; i < NBLK; ++i) {
    int n0 = 1 + i * TBLK;
    int size = NN - 1 - n0;
    if (size > TBLK) size = TBLK;
    gemm_partial<1><<<64, 256, 0, stream>>>(curT, W_mid, adjN, CfullT, NN, n0, size, 64, 2);
    seq_block<<<1, 256, 0, stream>>>(wpack, nl_idx, b_mid, CfullT, curT, i, n0, size);
  }

  gemm_partial<2><<<128, 256, 0, stream>>>(curT, W_out, adjN, outaccT, DOUT, 0, DOUT, 128, 8);
  final_finish<<<128, 256, 0, stream>>>(outaccT, b_out, nl_idx, out);
  transpose_state<<<32, 256, 0, stream>>>(curT, stateOut);
}